// Round 2
// baseline (7162.397 us; speedup 1.0000x reference)
//
#include <hip/hip_runtime.h>
#include <hip/hip_bf16.h>
#include <stdint.h>

#define BATCH 64
#define SEQ   512
#define INDIM 1024
#define HDIM  1024
#define NGRP_BLK 32   // blocks per m-group in the scan (128 blocks / 4 groups)

typedef short bf16x8 __attribute__((ext_vector_type(8)));
typedef short s16x4  __attribute__((ext_vector_type(4)));
typedef float f32x4  __attribute__((ext_vector_type(4)));
typedef unsigned short u16;
typedef unsigned short u16x4 __attribute__((ext_vector_type(4)));

static __device__ __forceinline__ u16 f2bf(float x) {
  unsigned int u = __float_as_uint(x);
  u += 0x7fffu + ((u >> 16) & 1u);
  return (u16)(u >> 16);
}
static __device__ __forceinline__ float bf2f(u16 b) {
  return __uint_as_float(((unsigned int)b) << 16);
}
static __device__ __forceinline__ void split4(float4 v, u16x4& hi, u16x4& lo) {
  hi.x = f2bf(v.x); lo.x = f2bf(v.x - bf2f(hi.x));
  hi.y = f2bf(v.y); lo.y = f2bf(v.y - bf2f(hi.y));
  hi.z = f2bf(v.z); lo.z = f2bf(v.z - bf2f(hi.z));
  hi.w = f2bf(v.w); lo.w = f2bf(v.w - bf2f(hi.w));
}
static __device__ __forceinline__ bf16x8 ld8(const u16* p) {
  s16x4 a = *(const s16x4*)p;
  s16x4 b = *(const s16x4*)(p + 4);
  return __builtin_shufflevector(a, b, 0, 1, 2, 3, 4, 5, 6, 7);
}

// ---- init: zero barrier counters, split h0 into bf16 hi/lo ----
__global__ void init_kernel(const float* __restrict__ h0, u16* __restrict__ hhi,
                            u16* __restrict__ hlo, int* __restrict__ cnt) {
  int i = blockIdx.x * blockDim.x + threadIdx.x;
  if (i < 4 * SEQ) cnt[i] = 0;
  if (i < BATCH * HDIM) {
    float x = h0[i];
    u16 h = f2bf(x);
    hhi[i] = h;
    hlo[i] = f2bf(x - bf2f(h));
  }
}

// ---- phase 1: xp = X @ W_ih^T + b_ih + b_hh via split-bf16 MFMA ----
// A [32768,1024] fp32, W [1024,1024] fp32 (row = output col), C [32768,1024] fp32
__global__ __launch_bounds__(256) void xproj_kernel(const float* __restrict__ A,
                                                    const float* __restrict__ W,
                                                    const float* __restrict__ bih,
                                                    const float* __restrict__ bhh,
                                                    float* __restrict__ C) {
  // [k-group][row][8 + 4 pad] — pad makes row stride 24B: b64 reads/writes ~conflict-free
  __shared__ u16 Ah[4][128][12], Al[4][128][12], Bh[4][128][12], Bl[4][128][12];
  const int nb = blockIdx.x;   // 0..7   (fast dim: 8 consecutive blocks share A panel)
  const int mb = blockIdx.y;   // 0..255
  const int m_base = mb * 128, n_base = nb * 128;
  const int tid = (int)threadIdx.x;
  const int wid = tid >> 6, lane = tid & 63;
  const int wm = wid >> 1, wn = wid & 1;
  const int r = lane & 15, kg = lane >> 4;
  const int srow = tid >> 1;            // 0..127
  const int skq  = (tid & 1) * 16;      // 0 or 16

  const float* ap0 = A + (size_t)(m_base + srow) * INDIM + skq;
  const float* bp0 = W + (size_t)(n_base + srow) * INDIM + skq;

  f32x4 acc[4][4] = {};

  for (int k0 = 0; k0 < INDIM; k0 += 32) {
    float4 av[4], bv[4];
#pragma unroll
    for (int i = 0; i < 4; ++i) {
      av[i] = *(const float4*)(ap0 + k0 + i * 4);
      bv[i] = *(const float4*)(bp0 + k0 + i * 4);
    }
    __syncthreads();  // previous iteration's reads done
#pragma unroll
    for (int i = 0; i < 4; ++i) {
      int kk = skq + i * 4;
      int kgw = kk >> 3, off = kk & 7;
      u16x4 hi, lo;
      split4(av[i], hi, lo);
      *(u16x4*)&Ah[kgw][srow][off] = hi;
      *(u16x4*)&Al[kgw][srow][off] = lo;
      split4(bv[i], hi, lo);
      *(u16x4*)&Bh[kgw][srow][off] = hi;
      *(u16x4*)&Bl[kgw][srow][off] = lo;
    }
    __syncthreads();

    bf16x8 ah[4], al[4], bhv[4], blv[4];
#pragma unroll
    for (int mf = 0; mf < 4; ++mf) {
      int row = wm * 64 + mf * 16 + r;
      ah[mf] = ld8(&Ah[kg][row][0]);
      al[mf] = ld8(&Al[kg][row][0]);
    }
#pragma unroll
    for (int nf = 0; nf < 4; ++nf) {
      int row = wn * 64 + nf * 16 + r;
      bhv[nf] = ld8(&Bh[kg][row][0]);
      blv[nf] = ld8(&Bl[kg][row][0]);
    }
#pragma unroll
    for (int mf = 0; mf < 4; ++mf)
#pragma unroll
      for (int nf = 0; nf < 4; ++nf) {
        acc[mf][nf] = __builtin_amdgcn_mfma_f32_16x16x32_bf16(ah[mf], bhv[nf], acc[mf][nf], 0, 0, 0);
        acc[mf][nf] = __builtin_amdgcn_mfma_f32_16x16x32_bf16(ah[mf], blv[nf], acc[mf][nf], 0, 0, 0);
        acc[mf][nf] = __builtin_amdgcn_mfma_f32_16x16x32_bf16(al[mf], bhv[nf], acc[mf][nf], 0, 0, 0);
      }
  }

#pragma unroll
  for (int nf = 0; nf < 4; ++nf) {
    int col = n_base + wn * 64 + nf * 16 + r;
    float bias = bih[col] + bhh[col];
#pragma unroll
    for (int mf = 0; mf < 4; ++mf) {
      int rowb = m_base + wm * 64 + mf * 16 + kg * 4;
#pragma unroll
      for (int q = 0; q < 4; ++q) {
        C[(size_t)(rowb + q) * HDIM + col] = acc[mf][nf][q] + bias;
      }
    }
  }
}

// ---- phase 2: persistent cooperative scan over 512 timesteps ----
// 128 blocks x 128 threads. Block b: m-group g=b&3 (batch rows 16g..16g+15),
// n-slice ns=b>>2 (hidden cols 32ns..32ns+31). W_hh slice resident in LDS.
__global__ __launch_bounds__(128) void rnn_scan(const float* __restrict__ Whh,
                                                float* out,
                                                u16* __restrict__ h0hi, u16* __restrict__ h0lo,
                                                u16* __restrict__ h1hi, u16* __restrict__ h1lo,
                                                int* cnt) {
  __shared__ u16 Wh[128][32][8];  // [k-group][local n row][8] — 64 KB
  __shared__ u16 Wl[128][32][8];  // 64 KB
  const int b = (int)blockIdx.x;
  const int g = b & 3;
  const int ns = b >> 2;
  const int n0 = ns * 32;
  const int tid = (int)threadIdx.x;
  const int wave = tid >> 6, lane = tid & 63;
  const int r = lane & 15, kg = lane >> 4;

  // stage W_hh rows n0..n0+31 into LDS, split hi/lo (one-time)
  for (int it = 0; it < 64; ++it) {
    int p = (it * 128 + tid) * 4;   // element index within 32x1024 slice
    int row = p >> 10, k = p & 1023;
    float4 v = *(const float4*)(Whh + (size_t)(n0 + row) * HDIM + k);
    u16x4 hi, lo;
    split4(v, hi, lo);
    *(u16x4*)&Wh[k >> 3][row][k & 7] = hi;
    *(u16x4*)&Wl[k >> 3][row][k & 7] = lo;
  }
  __syncthreads();

  u16* hhi[2] = {h0hi, h1hi};
  u16* hlo[2] = {h0lo, h1lo};
  const int m0 = g * 16;
  const int arow = (m0 + r) * HDIM;
  const int colL = wave * 16 + r;   // 0..31 local W row
  const int col = n0 + colL;

  for (int t = 0; t < SEQ; ++t) {
    const u16* ahi = hhi[t & 1];
    const u16* alo = hlo[t & 1];
    u16* nhi = hhi[(t + 1) & 1];
    u16* nlo = hlo[(t + 1) & 1];

    // issue xp reads early to overlap with the MFMA loop
    size_t oidx[4];
    float xp[4];
#pragma unroll
    for (int q = 0; q < 4; ++q) {
      int row = m0 + kg * 4 + q;
      oidx[q] = ((size_t)row * SEQ + t) * (size_t)HDIM + col;
      xp[q] = out[oidx[q]];
    }

    f32x4 acc = {0.f, 0.f, 0.f, 0.f};
#pragma unroll 4
    for (int k0 = 0; k0 < HDIM; k0 += 32) {
      int ka = k0 + kg * 8;
      bf16x8 ah = *(const bf16x8*)(ahi + arow + ka);
      bf16x8 al = *(const bf16x8*)(alo + arow + ka);
      bf16x8 bh = *(const bf16x8*)&Wh[ka >> 3][colL][0];
      bf16x8 bl = *(const bf16x8*)&Wl[ka >> 3][colL][0];
      acc = __builtin_amdgcn_mfma_f32_16x16x32_bf16(ah, bh, acc, 0, 0, 0);
      acc = __builtin_amdgcn_mfma_f32_16x16x32_bf16(ah, bl, acc, 0, 0, 0);
      acc = __builtin_amdgcn_mfma_f32_16x16x32_bf16(al, bh, acc, 0, 0, 0);
    }

#pragma unroll
    for (int q = 0; q < 4; ++q) {
      int row = m0 + kg * 4 + q;
      float v = xp[q] + acc[q];
      v = v > 0.f ? v : 0.f;
      out[oidx[q]] = v;
      u16 hv = f2bf(v);
      nhi[row * HDIM + col] = hv;
      nlo[row * HDIM + col] = f2bf(v - bf2f(hv));
    }

    // per-m-group barrier: wait until all 32 blocks of group g finished step t
    __syncthreads();
    if (tid == 0) {
      __threadfence();  // push this XCD's writes to device coherence point
      __hip_atomic_fetch_add(&cnt[g * SEQ + t], 1, __ATOMIC_RELAXED, __HIP_MEMORY_SCOPE_AGENT);
      while (__hip_atomic_load(&cnt[g * SEQ + t], __ATOMIC_RELAXED, __HIP_MEMORY_SCOPE_AGENT) < NGRP_BLK)
        __builtin_amdgcn_s_sleep(1);
      __threadfence();  // invalidate stale caches before next step's reads
    }
    __syncthreads();
  }
}

// ---- h_n = outputs[:, SEQ-1, :] ----
__global__ void copy_hn(const float* __restrict__ out, float* __restrict__ hn) {
  int idx = blockIdx.x * blockDim.x + threadIdx.x;
  if (idx < BATCH * HDIM) {
    int b = idx >> 10, j = idx & 1023;
    hn[idx] = out[((size_t)b * SEQ + (SEQ - 1)) * (size_t)HDIM + j];
  }
}

extern "C" void kernel_launch(void* const* d_in, const int* in_sizes, int n_in,
                              void* d_out, int out_size, void* d_ws, size_t ws_size,
                              hipStream_t stream) {
  const float* inputs = (const float*)d_in[0];
  const float* h0     = (const float*)d_in[1];
  const float* w_ih   = (const float*)d_in[2];
  const float* w_hh   = (const float*)d_in[3];
  const float* b_ih   = (const float*)d_in[4];
  const float* b_hh   = (const float*)d_in[5];

  float* outBase = (float*)d_out;
  float* hnBase  = outBase + (size_t)BATCH * SEQ * HDIM;

  // ws: h ping-pong hi/lo (4 x 128 KB) + barrier counters (8 KB)
  u16* hb = (u16*)d_ws;
  u16* h_hi0 = hb;
  u16* h_lo0 = hb + (size_t)BATCH * HDIM;
  u16* h_hi1 = hb + 2 * (size_t)BATCH * HDIM;
  u16* h_lo1 = hb + 3 * (size_t)BATCH * HDIM;
  int* cnt = (int*)(hb + 4 * (size_t)BATCH * HDIM);

  init_kernel<<<256, 256, 0, stream>>>(h0, h_hi0, h_lo0, cnt);

  xproj_kernel<<<dim3(8, 256), 256, 0, stream>>>(inputs, w_ih, b_ih, b_hh, outBase);

  const float* whh_a = w_hh;
  float* out_a = outBase;
  u16 *a0 = h_hi0, *a1 = h_lo0, *a2 = h_hi1, *a3 = h_lo1;
  int* c_a = cnt;
  void* args[7] = {&whh_a, &out_a, &a0, &a1, &a2, &a3, &c_a};
  hipLaunchCooperativeKernel((const void*)rnn_scan, dim3(128), dim3(128), args, 0, stream);

  copy_hn<<<256, 256, 0, stream>>>(outBase, hnBase);
}

// Round 4
// 2358.042 us; speedup vs baseline: 3.0374x; 3.0374x over previous
//
#include <hip/hip_runtime.h>
#include <hip/hip_bf16.h>
#include <stdint.h>

#define BATCH 64
#define SEQ   512
#define INDIM 1024
#define HDIM  1024
#define NGRP  4      // batch groups of 16 rows
#define BPG   64     // blocks per group (each owns 16 hidden cols)

typedef short bf16x8 __attribute__((ext_vector_type(8)));
typedef float f32x4  __attribute__((ext_vector_type(4)));
typedef unsigned short u16;
typedef unsigned int   u32;
typedef u32 u32x4 __attribute__((ext_vector_type(4)));

static __device__ __forceinline__ u16 f2bf(float x) {
  unsigned int u = __float_as_uint(x);
  u += 0x7fffu + ((u >> 16) & 1u);
  return (u16)(u >> 16);
}
static __device__ __forceinline__ float bf2f(u16 b) {
  return __uint_as_float(((unsigned int)b) << 16);
}

// coherent (device-scope, L1/L2-bypass) scalar load for flag polling
static __device__ __forceinline__ int coh_ld_i32(const int* p) {
  int v;
  asm volatile("global_load_dword %0, %1, off sc0 sc1\n\t"
               "s_waitcnt vmcnt(0)"
               : "=&v"(v) : "v"(p) : "memory");
  return v;
}

static __device__ __forceinline__ void split8(float4 a, float4 b, bf16x8& hi, bf16x8& lo) {
  union { u16 u[8]; bf16x8 v; } H, L;
  float f[8] = {a.x, a.y, a.z, a.w, b.x, b.y, b.z, b.w};
#pragma unroll
  for (int i = 0; i < 8; ++i) {
    u16 h = f2bf(f[i]);
    H.u[i] = h;
    L.u[i] = f2bf(f[i] - bf2f(h));
  }
  hi = H.v; lo = L.v;
}

// ---- init: zero flags, pack h0 into fragment-major hi|lo layout ----
// hpack slot: [(g*32 + k32)*64 + kg*16 + r] -> 16 u16 (8 hi | 8 lo)
// holds h[g*16 + r][k32*32 + kg*8 + j]
__global__ void init_kernel(const float* __restrict__ h0, u16* __restrict__ hbuf0,
                            int* __restrict__ cnt) {
  int i = blockIdx.x * blockDim.x + threadIdx.x;
  if (i < NGRP * SEQ) cnt[i] = 0;
  if (i < BATCH * HDIM) {
    int b = i >> 10, k = i & 1023;
    int g = b >> 4, r = b & 15;
    int k32 = k >> 5, kg = (k >> 3) & 3, j = k & 7;
    float x = h0[i];
    u16 h = f2bf(x);
    size_t u = ((size_t)(g * 32 + k32) * 64 + kg * 16 + r) * 16 + j;
    hbuf0[u] = h;
    hbuf0[u + 8] = f2bf(x - bf2f(h));
  }
}

// ---- fused persistent scan: h_t = relu(x_t Wih^T + b + h_{t-1} Whh^T) ----
// 256 blocks x 512 thr. Block b: group g=b&3 (16 batch rows), cols c=b>>2 (16).
// 8 waves K-split 128 each; W slices (hi/lo, both mats) resident in LDS.
__global__ __launch_bounds__(512, 1) void rnn_fused(
    const float* __restrict__ X, const float* __restrict__ Wih,
    const float* __restrict__ Whh, const float* __restrict__ bih,
    const float* __restrict__ bhh, float* __restrict__ out,
    u16* hbuf0, u16* hbuf1, int* cnt) {
  __shared__ u16 WihH[32][64][8], WihL[32][64][8];
  __shared__ u16 WhhH[32][64][8], WhhL[32][64][8];
  __shared__ float red[8][16][16];
  __shared__ float biasS[16];

  const int blk = (int)blockIdx.x;
  const int g = blk & 3;
  const int c = blk >> 2;
  const int m0 = g * 16;
  const int n0 = c * 16;
  const int tid = (int)threadIdx.x;
  const int wv = tid >> 6, lane = tid & 63;
  const int r = lane & 15, kg = lane >> 4;

  // ---- one-time: stage W slices into LDS, fragment-major, split hi/lo ----
  for (int mat = 0; mat < 2; ++mat) {
    const float* W = mat ? Whh : Wih;
    u16 (*Lh)[64][8] = mat ? WhhH : WihH;
    u16 (*Ll)[64][8] = mat ? WhhL : WihL;
    for (int it = 0; it < 8; ++it) {
      int f4 = it * 512 + tid;            // float4 index in 16x1024 slice
      int row = f4 >> 8;                  // 0..15
      int k0 = (f4 & 255) * 4;            // 0..1020
      float4 v = *(const float4*)(W + (size_t)(n0 + row) * INDIM + k0);
      int k32 = k0 >> 5, kgg = (k0 >> 3) & 3, j = k0 & 7;
      int ln = kgg * 16 + row;
      u16* ph = &Lh[k32][ln][j];
      u16* pl = &Ll[k32][ln][j];
      u16 h;
      h = f2bf(v.x); ph[0] = h; pl[0] = f2bf(v.x - bf2f(h));
      h = f2bf(v.y); ph[1] = h; pl[1] = f2bf(v.y - bf2f(h));
      h = f2bf(v.z); ph[2] = h; pl[2] = f2bf(v.z - bf2f(h));
      h = f2bf(v.w); ph[3] = h; pl[3] = f2bf(v.w - bf2f(h));
    }
  }
  if (tid < 16) biasS[tid] = bih[n0 + tid] + bhh[n0 + tid];
  __syncthreads();

  // x prefetch registers (this wave's K-range of step t)
  const size_t xbase = ((size_t)(m0 + r) * SEQ) * INDIM + (size_t)(wv * 128 + kg * 8);
  float4 xf[8];
#pragma unroll
  for (int i = 0; i < 4; ++i) {
    xf[2 * i]     = *(const float4*)(X + xbase + i * 32);
    xf[2 * i + 1] = *(const float4*)(X + xbase + i * 32 + 4);
  }

  const size_t gofs = (size_t)g << 16;  // group offset in hpack (bytes)

  for (int t = 0; t < SEQ; ++t) {
    const char* hc = (const char*)(t & 1 ? hbuf1 : hbuf0) + gofs;
    char*       hn = (char*)      (t & 1 ? hbuf0 : hbuf1) + gofs;

    // (a) wait until h(t) fully stored by all group-mates
    if (t > 0) {
      if (tid == 0) {
        const int* f = &cnt[g * SEQ + (t - 1)];
        while (coh_ld_i32(f) < BPG) __builtin_amdgcn_s_sleep(1);
      }
      __syncthreads();
    }

    // (b) coherent-load this wave's h A-fragments (8 x 16B, pipelined)
    u32x4 hh[4], hl[4];
    const char* a0 = hc + (size_t)((wv * 4 + 0) * 64 + lane) * 32;
    const char* a1 = hc + (size_t)((wv * 4 + 2) * 64 + lane) * 32;
    asm volatile(
        "global_load_dwordx4 %0, %8, off sc0 sc1\n\t"
        "global_load_dwordx4 %1, %8, off offset:16 sc0 sc1\n\t"
        "global_load_dwordx4 %2, %8, off offset:2048 sc0 sc1\n\t"
        "global_load_dwordx4 %3, %8, off offset:2064 sc0 sc1\n\t"
        "global_load_dwordx4 %4, %9, off sc0 sc1\n\t"
        "global_load_dwordx4 %5, %9, off offset:16 sc0 sc1\n\t"
        "global_load_dwordx4 %6, %9, off offset:2048 sc0 sc1\n\t"
        "global_load_dwordx4 %7, %9, off offset:2064 sc0 sc1"
        : "=&v"(hh[0]), "=&v"(hl[0]), "=&v"(hh[1]), "=&v"(hl[1]),
          "=&v"(hh[2]), "=&v"(hl[2]), "=&v"(hh[3]), "=&v"(hl[3])
        : "v"(a0), "v"(a1)
        : "memory");
    asm volatile("s_waitcnt vmcnt(0)"
        : "+v"(hh[0]), "+v"(hl[0]), "+v"(hh[1]), "+v"(hl[1]),
          "+v"(hh[2]), "+v"(hl[2]), "+v"(hh[3]), "+v"(hl[3]));

    f32x4 acc = {0.f, 0.f, 0.f, 0.f};
#pragma unroll
    for (int i = 0; i < 4; ++i) {
      int k32 = wv * 4 + i;
      bf16x8 ah = __builtin_bit_cast(bf16x8, hh[i]);
      bf16x8 al = __builtin_bit_cast(bf16x8, hl[i]);
      bf16x8 bh = *(const bf16x8*)&WhhH[k32][lane][0];
      bf16x8 bl = *(const bf16x8*)&WhhL[k32][lane][0];
      acc = __builtin_amdgcn_mfma_f32_16x16x32_bf16(ah, bh, acc, 0, 0, 0);
      acc = __builtin_amdgcn_mfma_f32_16x16x32_bf16(ah, bl, acc, 0, 0, 0);
      acc = __builtin_amdgcn_mfma_f32_16x16x32_bf16(al, bh, acc, 0, 0, 0);
      bf16x8 xh, xl;
      split8(xf[2 * i], xf[2 * i + 1], xh, xl);
      bf16x8 wh = *(const bf16x8*)&WihH[k32][lane][0];
      bf16x8 wl = *(const bf16x8*)&WihL[k32][lane][0];
      acc = __builtin_amdgcn_mfma_f32_16x16x32_bf16(xh, wh, acc, 0, 0, 0);
      acc = __builtin_amdgcn_mfma_f32_16x16x32_bf16(xh, wl, acc, 0, 0, 0);
      acc = __builtin_amdgcn_mfma_f32_16x16x32_bf16(xl, wh, acc, 0, 0, 0);
    }

    // (c) cross-wave K-reduction. D layout: n = lane&15, m = kg*4+q
#pragma unroll
    for (int q = 0; q < 4; ++q) red[wv][kg * 4 + q][r] = acc[q];
    __syncthreads();

    if (tid < 32) {
      int rr = tid >> 1, o = tid & 1;   // row, col-octet
      float v[8];
#pragma unroll
      for (int j = 0; j < 8; ++j) {
        float s = biasS[o * 8 + j];
#pragma unroll
        for (int w = 0; w < 8; ++w) s += red[w][rr][o * 8 + j];
        v[j] = s > 0.f ? s : 0.f;
      }
      // outputs (write-only, non-temporal)
      float* op = out + ((size_t)(m0 + rr) * SEQ + t) * HDIM + n0 + o * 8;
      f32x4 o0 = {v[0], v[1], v[2], v[3]}, o1 = {v[4], v[5], v[6], v[7]};
      __builtin_nontemporal_store(o0, (f32x4*)op);
      __builtin_nontemporal_store(o1, (f32x4*)(op + 4));
      // pack h(t+1) hi/lo and store coherently
      union { u16 u[8]; u32x4 q; } HH, LL;
#pragma unroll
      for (int j = 0; j < 8; ++j) {
        u16 h = f2bf(v[j]);
        HH.u[j] = h;
        LL.u[j] = f2bf(v[j] - bf2f(h));
      }
      int kk = n0 + o * 8;
      int k32 = kk >> 5, kgg = (kk >> 3) & 3;
      char* hp = hn + (size_t)(k32 * 64 + kgg * 16 + rr) * 32;
      asm volatile(
          "global_store_dwordx4 %0, %1, off sc0 sc1\n\t"
          "global_store_dwordx4 %0, %2, off offset:16 sc0 sc1\n\t"
          "s_waitcnt vmcnt(0)"
          :: "v"(hp), "v"(HH.q), "v"(LL.q)
          : "memory");
    }
    __syncthreads();
    if (tid == 0)
      __hip_atomic_fetch_add(&cnt[g * SEQ + t], 1, __ATOMIC_RELAXED, __HIP_MEMORY_SCOPE_AGENT);

    // (e) prefetch x(t+1) — latency hides under next poll
    if (t + 1 < SEQ) {
      const float* xp = X + xbase + (size_t)(t + 1) * INDIM;
#pragma unroll
      for (int i = 0; i < 4; ++i) {
        xf[2 * i]     = *(const float4*)(xp + i * 32);
        xf[2 * i + 1] = *(const float4*)(xp + i * 32 + 4);
      }
    }
  }
}

// ---- h_n = outputs[:, SEQ-1, :] ----
__global__ void copy_hn(const float* __restrict__ out, float* __restrict__ hn) {
  int idx = blockIdx.x * blockDim.x + threadIdx.x;
  if (idx < BATCH * HDIM) {
    int b = idx >> 10, j = idx & 1023;
    hn[idx] = out[((size_t)b * SEQ + (SEQ - 1)) * (size_t)HDIM + j];
  }
}

extern "C" void kernel_launch(void* const* d_in, const int* in_sizes, int n_in,
                              void* d_out, int out_size, void* d_ws, size_t ws_size,
                              hipStream_t stream) {
  const float* inputs = (const float*)d_in[0];
  const float* h0     = (const float*)d_in[1];
  const float* w_ih   = (const float*)d_in[2];
  const float* w_hh   = (const float*)d_in[3];
  const float* b_ih   = (const float*)d_in[4];
  const float* b_hh   = (const float*)d_in[5];

  float* outBase = (float*)d_out;
  float* hnBase  = outBase + (size_t)BATCH * SEQ * HDIM;

  // ws: hpack ping-pong (2 x 256 KB) + flags (8 KB)
  u16* hbuf0 = (u16*)d_ws;
  u16* hbuf1 = hbuf0 + (size_t)NGRP * 32 * 64 * 16;
  int* cnt   = (int*)(hbuf1 + (size_t)NGRP * 32 * 64 * 16);

  init_kernel<<<256, 256, 0, stream>>>(h0, hbuf0, cnt);

  const float* xa = inputs;
  const float* wia = w_ih;
  const float* wha = w_hh;
  const float* bia = b_ih;
  const float* bha = b_hh;
  float* oa = outBase;
  u16 *hb0 = hbuf0, *hb1 = hbuf1;
  int* ca = cnt;
  void* args[9] = {&xa, &wia, &wha, &bia, &bha, &oa, &hb0, &hb1, &ca};
  hipLaunchCooperativeKernel((const void*)rnn_fused, dim3(NGRP * BPG), dim3(512), args, 0, stream);

  copy_hn<<<256, 256, 0, stream>>>(outBase, hnBase);
}